// Round 1
// baseline (151.522 us; speedup 1.0000x reference)
//
#include <hip/hip_runtime.h>
#include <math.h>

#define N      512
#define RNUM   4
#define BNUM   2
#define NSLICE (RNUM * BNUM)
#define TILE   64
#define CT     64
#define PAD    4   // row stride TILE+PAD = 68 floats = 272 B, 16B-aligned rows

__device__ __forceinline__ float sigmoidf_(float x) {
  return 1.0f / (1.0f + __expf(-x));
}

__global__ void zero_out_kernel(float* out) { out[0] = 0.0f; }

// One thread per (b,i,j): reads float4 over r (innermost dim), writes 4 slice
// planes P[(b*R+r)*N*N + i*N + j] with sigmoid + mask applied.
__global__ __launch_bounds__(256) void prep_kernel(const float* __restrict__ logits,
                                                   const int* __restrict__ masks,
                                                   float* __restrict__ P) {
  int t = blockIdx.x * 256 + threadIdx.x;      // 0 .. B*N*N-1
  int b = t / (N * N);
  int rem = t - b * (N * N);
  int i = rem / N;
  int j = rem - i * N;
  float4 lg = *(const float4*)(logits + (size_t)t * 4);
  float mm = ((masks[b * N + i] > 0) && (masks[b * N + j] > 0)) ? 1.0f : 0.0f;
  size_t base = (size_t)b * RNUM * N * N + rem;
  P[base + 0 * (size_t)N * N] = mm * sigmoidf_(lg.x);
  P[base + 1 * (size_t)N * N] = mm * sigmoidf_(lg.y);
  P[base + 2 * (size_t)N * N] = mm * sigmoidf_(lg.z);
  P[base + 3 * (size_t)N * N] = mm * sigmoidf_(lg.w);
}

// Block: one (slice, 64x64 (a,b) tile). Thread: 4x4 register block.
// LDS tiles transposed: t[c][i] = rel[row0+i][c0+c].
template <bool USE_P>
__global__ __launch_bounds__(256) void trans_main_kernel(const float* __restrict__ P,
                                                         const float* __restrict__ logits,
                                                         const int* __restrict__ masks,
                                                         float* __restrict__ out) {
  const int s  = blockIdx.z;     // 0..7 : slice = b*R + r
  const int at = blockIdx.y;
  const int bt = blockIdx.x;
  const int a0 = at * TILE;
  const int b0 = bt * TILE;
  const int bb = s >> 2;
  const int r  = s & 3;

  __shared__ __align__(16) float tA[CT][TILE + PAD];
  __shared__ __align__(16) float tB[CT][TILE + PAD];
  __shared__ float wsum[4];

  const int tid = threadIdx.x;
  const int ta  = tid & 15;     // a-group: rows a0 + ta*4 .. +3
  const int tb  = tid >> 4;     // b-group: rows b0 + tb*4 .. +3

  const float* Ps  = P + (size_t)s * N * N;
  const int* mrow  = masks + bb * N;

  // rel[a][b] for this thread's 4x4 pairs
  float rab[4][4];
  if (USE_P) {
#pragma unroll
    for (int x = 0; x < 4; ++x)
#pragma unroll
      for (int y = 0; y < 4; ++y)
        rab[x][y] = Ps[(size_t)(a0 + ta * 4 + x) * N + (b0 + tb * 4 + y)];
  } else {
    float ma[4], mb[4];
#pragma unroll
    for (int x = 0; x < 4; ++x) ma[x] = (mrow[a0 + ta * 4 + x] > 0) ? 1.0f : 0.0f;
#pragma unroll
    for (int y = 0; y < 4; ++y) mb[y] = (mrow[b0 + tb * 4 + y] > 0) ? 1.0f : 0.0f;
#pragma unroll
    for (int x = 0; x < 4; ++x)
#pragma unroll
      for (int y = 0; y < 4; ++y) {
        size_t idx = ((size_t)(bb * N + a0 + ta * 4 + x) * N + (b0 + tb * 4 + y)) * RNUM + r;
        rab[x][y] = sigmoidf_(logits[idx]) * ma[x] * mb[y];
      }
  }

  float acc[4][4];
#pragma unroll
  for (int x = 0; x < 4; ++x)
#pragma unroll
    for (int y = 0; y < 4; ++y) acc[x][y] = 0.0f;

  for (int c0 = 0; c0 < N; c0 += CT) {
    __syncthreads();
    if (USE_P) {
      // 1024 float4s per tile, 4 per thread; f -> (c4 = f&15, i = f>>4)
#pragma unroll
      for (int it = 0; it < 4; ++it) {
        int f  = it * 256 + tid;
        int c4 = f & 15;
        int i  = f >> 4;
        float4 va = *(const float4*)(Ps + (size_t)(a0 + i) * N + c0 + c4 * 4);
        tA[c4 * 4 + 0][i] = va.x;
        tA[c4 * 4 + 1][i] = va.y;
        tA[c4 * 4 + 2][i] = va.z;
        tA[c4 * 4 + 3][i] = va.w;
        float4 vb = *(const float4*)(Ps + (size_t)(b0 + i) * N + c0 + c4 * 4);
        tB[c4 * 4 + 0][i] = vb.x;
        tB[c4 * 4 + 1][i] = vb.y;
        tB[c4 * 4 + 2][i] = vb.z;
        tB[c4 * 4 + 3][i] = vb.w;
      }
    } else {
      // scalar on-the-fly sigmoid fallback (no workspace)
#pragma unroll
      for (int it = 0; it < 16; ++it) {
        int e = it * 256 + tid;
        int c = e & 63;
        int i = e >> 6;
        float mc = (mrow[c0 + c] > 0) ? 1.0f : 0.0f;
        {
          float mi = (mrow[a0 + i] > 0) ? 1.0f : 0.0f;
          size_t idx = ((size_t)(bb * N + a0 + i) * N + (c0 + c)) * RNUM + r;
          tA[c][i] = sigmoidf_(logits[idx]) * mi * mc;
        }
        {
          float mi = (mrow[b0 + i] > 0) ? 1.0f : 0.0f;
          size_t idx = ((size_t)(bb * N + b0 + i) * N + (c0 + c)) * RNUM + r;
          tB[c][i] = sigmoidf_(logits[idx]) * mi * mc;
        }
      }
    }
    __syncthreads();

#pragma unroll 4
    for (int c = 0; c < CT; ++c) {
      float4 va4 = *(const float4*)&tA[c][ta * 4];
      float4 vb4 = *(const float4*)&tB[c][tb * 4];
      float av[4] = {va4.x, va4.y, va4.z, va4.w};
      float bv[4] = {vb4.x, vb4.y, vb4.z, vb4.w};
#pragma unroll
      for (int x = 0; x < 4; ++x)
#pragma unroll
        for (int y = 0; y < 4; ++y) {
          float v = fmaf(-av[x], bv[y], rab[x][y]);
          acc[x][y] += fmaxf(v, 0.0f);
        }
    }
  }

  // reduction: thread -> wave -> block -> global atomic
  float tsum = 0.0f;
#pragma unroll
  for (int x = 0; x < 4; ++x)
#pragma unroll
    for (int y = 0; y < 4; ++y) tsum += acc[x][y];

  for (int off = 32; off > 0; off >>= 1) tsum += __shfl_down(tsum, off, 64);

  const int wid  = tid >> 6;
  const int lane = tid & 63;
  if (lane == 0) wsum[wid] = tsum;
  __syncthreads();
  if (tid == 0) {
    float bsum = wsum[0] + wsum[1] + wsum[2] + wsum[3];
    // WEIGHT * sum / (R*B) = sum / 8
    atomicAdd(out, bsum * 0.125f);
  }
}

extern "C" void kernel_launch(void* const* d_in, const int* in_sizes, int n_in,
                              void* d_out, int out_size, void* d_ws, size_t ws_size,
                              hipStream_t stream) {
  const float* logits = (const float*)d_in[0];
  const int*   masks  = (const int*)d_in[1];
  float*       out    = (float*)d_out;

  const size_t P_BYTES = (size_t)NSLICE * N * N * sizeof(float);  // 8 MB

  zero_out_kernel<<<1, 1, 0, stream>>>(out);

  dim3 grid(N / TILE, N / TILE, NSLICE);  // (8, 8, 8) = 512 blocks
  if (ws_size >= P_BYTES) {
    float* P = (float*)d_ws;
    prep_kernel<<<(BNUM * N * N) / 256, 256, 0, stream>>>(logits, masks, P);
    trans_main_kernel<true><<<grid, 256, 0, stream>>>(P, logits, masks, out);
  } else {
    trans_main_kernel<false><<<grid, 256, 0, stream>>>(nullptr, logits, masks, out);
  }
}

// Round 2
// 137.841 us; speedup vs baseline: 1.0993x; 1.0993x over previous
//
#include <hip/hip_runtime.h>
#include <math.h>

#define N      512
#define RNUM   4
#define BNUM   2
#define NSLICE (RNUM * BNUM)
#define TILE   64
#define CT     64
#define PAD    4                 // stride 68 floats; bank math verified with this
#define STRIDE (TILE + PAD)
#define CSPLIT 2                 // blocks per slice along c -> 1024 blocks total

__device__ __forceinline__ float sigmoidf_(float x) {
  return 1.0f / (1.0f + __expf(-x));
}

__global__ void zero_out_kernel(float* out) { out[0] = 0.0f; }

// One thread per (b,i,j): reads float4 over r (innermost dim), writes 4 slice
// planes P[(b*R+r)*N*N + i*N + j] with sigmoid + mask applied.
__global__ __launch_bounds__(256) void prep_kernel(const float* __restrict__ logits,
                                                   const int* __restrict__ masks,
                                                   float* __restrict__ P) {
  int t = blockIdx.x * 256 + threadIdx.x;      // 0 .. B*N*N-1
  int b = t / (N * N);
  int rem = t - b * (N * N);
  int i = rem / N;
  int j = rem - i * N;
  float4 lg = *(const float4*)(logits + (size_t)t * 4);
  float mm = ((masks[b * N + i] > 0) && (masks[b * N + j] > 0)) ? 1.0f : 0.0f;
  size_t base = (size_t)b * RNUM * N * N + rem;
  P[base + 0 * (size_t)N * N] = mm * sigmoidf_(lg.x);
  P[base + 1 * (size_t)N * N] = mm * sigmoidf_(lg.y);
  P[base + 2 * (size_t)N * N] = mm * sigmoidf_(lg.z);
  P[base + 3 * (size_t)N * N] = mm * sigmoidf_(lg.w);
}

// Block: one (slice, 64x64 (a,b) tile, c-half). Thread: 4x4 register block.
// LDS tiles transposed with XOR swizzle: element t[r][i] stored at column
// pcol = (((i>>2) ^ ((r>>2)&15)) << 2) | (i&3).
// Bank math (stride 68): staging scalar writes 2-way (free), b128 reads 2-way
// (free), reads remain 16B-aligned contiguous float4.
template <bool USE_P>
__global__ __launch_bounds__(256, 4) void trans_main_kernel(const float* __restrict__ P,
                                                            const float* __restrict__ logits,
                                                            const int* __restrict__ masks,
                                                            float* __restrict__ out) {
  const int zz = blockIdx.z;
  const int s  = zz / CSPLIT;                 // slice = b*R + r
  const int cz = zz % CSPLIT;
  const int a0 = blockIdx.y * TILE;
  const int b0 = blockIdx.x * TILE;
  const int bb = s >> 2;
  const int r  = s & 3;
  const int cbeg = cz * (N / CSPLIT);
  const int cend = cbeg + (N / CSPLIT);

  __shared__ __align__(16) float tA[CT][STRIDE];
  __shared__ __align__(16) float tB[CT][STRIDE];
  __shared__ float wsum[4];

  const int tid = threadIdx.x;
  const int ta  = tid & 15;     // a-group: rows a0 + ta*4 .. +3
  const int tb  = tid >> 4;     // b-group: rows b0 + tb*4 .. +3

  const float* Ps  = P + (size_t)s * N * N;
  const int* mrow  = masks + bb * N;

  // rel[a][b] for this thread's 4x4 pairs
  float rab[4][4];
  if (USE_P) {
#pragma unroll
    for (int x = 0; x < 4; ++x) {
      float4 rr = *(const float4*)(Ps + (size_t)(a0 + ta * 4 + x) * N + b0 + tb * 4);
      rab[x][0] = rr.x; rab[x][1] = rr.y; rab[x][2] = rr.z; rab[x][3] = rr.w;
    }
  } else {
    float ma[4], mb[4];
#pragma unroll
    for (int x = 0; x < 4; ++x) ma[x] = (mrow[a0 + ta * 4 + x] > 0) ? 1.0f : 0.0f;
#pragma unroll
    for (int y = 0; y < 4; ++y) mb[y] = (mrow[b0 + tb * 4 + y] > 0) ? 1.0f : 0.0f;
#pragma unroll
    for (int x = 0; x < 4; ++x)
#pragma unroll
      for (int y = 0; y < 4; ++y) {
        size_t idx = ((size_t)(bb * N + a0 + ta * 4 + x) * N + (b0 + tb * 4 + y)) * RNUM + r;
        rab[x][y] = sigmoidf_(logits[idx]) * ma[x] * mb[y];
      }
  }

  float acc[4][4];
#pragma unroll
  for (int x = 0; x < 4; ++x)
#pragma unroll
    for (int y = 0; y < 4; ++y) acc[x][y] = 0.0f;

  for (int c0 = cbeg; c0 < cend; c0 += CT) {
    __syncthreads();
    if (USE_P) {
      // 1024 float4s per tile, 4 per thread; f -> (c4 = f&15, i = f>>4)
#pragma unroll
      for (int it = 0; it < 4; ++it) {
        int f  = it * 256 + tid;
        int c4 = f & 15;                       // c-group (= LDS row group r>>2)
        int i  = f >> 4;                       // tile row (a or b index)
        int pcol = (((i >> 2) ^ c4) << 2) | (i & 3);
        float4 va = *(const float4*)(Ps + (size_t)(a0 + i) * N + c0 + c4 * 4);
        tA[c4 * 4 + 0][pcol] = va.x;
        tA[c4 * 4 + 1][pcol] = va.y;
        tA[c4 * 4 + 2][pcol] = va.z;
        tA[c4 * 4 + 3][pcol] = va.w;
        float4 vb = *(const float4*)(Ps + (size_t)(b0 + i) * N + c0 + c4 * 4);
        tB[c4 * 4 + 0][pcol] = vb.x;
        tB[c4 * 4 + 1][pcol] = vb.y;
        tB[c4 * 4 + 2][pcol] = vb.z;
        tB[c4 * 4 + 3][pcol] = vb.w;
      }
    } else {
      // scalar on-the-fly sigmoid fallback (no workspace)
#pragma unroll
      for (int it = 0; it < 16; ++it) {
        int e = it * 256 + tid;
        int c = e & 63;
        int i = e >> 6;
        int pcol = (((i >> 2) ^ ((c >> 2) & 15)) << 2) | (i & 3);
        float mc = (mrow[c0 + c] > 0) ? 1.0f : 0.0f;
        {
          float mi = (mrow[a0 + i] > 0) ? 1.0f : 0.0f;
          size_t idx = ((size_t)(bb * N + a0 + i) * N + (c0 + c)) * RNUM + r;
          tA[c][pcol] = sigmoidf_(logits[idx]) * mi * mc;
        }
        {
          float mi = (mrow[b0 + i] > 0) ? 1.0f : 0.0f;
          size_t idx = ((size_t)(bb * N + b0 + i) * N + (c0 + c)) * RNUM + r;
          tB[c][pcol] = sigmoidf_(logits[idx]) * mi * mc;
        }
      }
    }
    __syncthreads();

#pragma unroll 4
    for (int cg = 0; cg < CT / 4; ++cg) {      // cg = c>>2 = swizzle key
      const float* pa = &tA[cg * 4][(ta ^ cg) << 2];
      const float* pb = &tB[cg * 4][(tb ^ cg) << 2];
#pragma unroll
      for (int dc = 0; dc < 4; ++dc) {
        float4 va4 = *(const float4*)(pa + dc * STRIDE);
        float4 vb4 = *(const float4*)(pb + dc * STRIDE);
        float av[4] = {va4.x, va4.y, va4.z, va4.w};
        float bv[4] = {vb4.x, vb4.y, vb4.z, vb4.w};
#pragma unroll
        for (int x = 0; x < 4; ++x)
#pragma unroll
          for (int y = 0; y < 4; ++y) {
            float v = fmaf(-av[x], bv[y], rab[x][y]);
            acc[x][y] += fmaxf(v, 0.0f);
          }
      }
    }
  }

  // reduction: thread -> wave -> block -> global atomic
  float tsum = 0.0f;
#pragma unroll
  for (int x = 0; x < 4; ++x)
#pragma unroll
    for (int y = 0; y < 4; ++y) tsum += acc[x][y];

  for (int off = 32; off > 0; off >>= 1) tsum += __shfl_down(tsum, off, 64);

  const int wid  = tid >> 6;
  const int lane = tid & 63;
  if (lane == 0) wsum[wid] = tsum;
  __syncthreads();
  if (tid == 0) {
    float bsum = wsum[0] + wsum[1] + wsum[2] + wsum[3];
    // WEIGHT * sum / (R*B) = sum / 8
    atomicAdd(out, bsum * 0.125f);
  }
}

extern "C" void kernel_launch(void* const* d_in, const int* in_sizes, int n_in,
                              void* d_out, int out_size, void* d_ws, size_t ws_size,
                              hipStream_t stream) {
  const float* logits = (const float*)d_in[0];
  const int*   masks  = (const int*)d_in[1];
  float*       out    = (float*)d_out;

  const size_t P_BYTES = (size_t)NSLICE * N * N * sizeof(float);  // 8 MB

  zero_out_kernel<<<1, 1, 0, stream>>>(out);

  dim3 grid(N / TILE, N / TILE, NSLICE * CSPLIT);  // (8, 8, 16) = 1024 blocks
  if (ws_size >= P_BYTES) {
    float* P = (float*)d_ws;
    prep_kernel<<<(BNUM * N * N) / 256, 256, 0, stream>>>(logits, masks, P);
    trans_main_kernel<true><<<grid, 256, 0, stream>>>(P, logits, masks, out);
  } else {
    trans_main_kernel<false><<<grid, 256, 0, stream>>>(nullptr, logits, masks, out);
  }
}